// Round 4
// baseline (1203.174 us; speedup 1.0000x reference)
//
#include <hip/hip_runtime.h>
#include <hip/hip_bf16.h>
#include <math.h>

#define B_TOK 8192
#define D_DIM 1024
#define H_DIM 4096
#define E_NUM 8
#define NPAIR (B_TOK * 2)

typedef __bf16 bf16x8 __attribute__((ext_vector_type(8)));
typedef float f32x4 __attribute__((ext_vector_type(4)));
typedef unsigned short us4 __attribute__((ext_vector_type(4)));

__device__ __forceinline__ unsigned short f2bf(float f) {
  union { float f; unsigned u; } v; v.f = f;
  unsigned r = v.u + 0x7FFFu + ((v.u >> 16) & 1u);
  return (unsigned short)(r >> 16);
}

__device__ __forceinline__ void gload16(const void* g, void* l) {
  __builtin_amdgcn_global_load_lds(
      (const __attribute__((address_space(1))) void*)g,
      (__attribute__((address_space(3))) void*)l, 16, 0, 0);
}

#define BARRIER()   asm volatile("s_barrier" ::: "memory")
#define WAIT_VM8()  asm volatile("s_waitcnt vmcnt(8)" ::: "memory")
#define WAIT_VM0()  asm volatile("s_waitcnt vmcnt(0)" ::: "memory")
#define WAIT_LGKM0() asm volatile("s_waitcnt lgkmcnt(0)" ::: "memory")

// ---------------- x fp32 -> bf16 ----------------
__global__ void k_convert_x(const float* __restrict__ x, unsigned short* __restrict__ xb) {
  int i = (blockIdx.x * 256 + threadIdx.x) * 4;
  float4 v = *(const float4*)(x + i);
  us4 o;
  o[0] = f2bf(v.x); o[1] = f2bf(v.y); o[2] = f2bf(v.z); o[3] = f2bf(v.w);
  *(us4*)(xb + i) = o;
}

// -------- (E, rows, cols) fp32 -> (E, cols, rows) bf16 --------
__global__ void k_transpose_bf16(const float* __restrict__ in, unsigned short* __restrict__ out,
                                 int rows, int cols) {
  __shared__ float t[32][33];
  const float* ine = in + (size_t)blockIdx.z * rows * cols;
  unsigned short* oute = out + (size_t)blockIdx.z * rows * cols;
  int c0 = blockIdx.x * 32, r0 = blockIdx.y * 32;
  int tx = threadIdx.x, ty = threadIdx.y;
#pragma unroll
  for (int j = 0; j < 32; j += 8)
    t[ty + j][tx] = ine[(size_t)(r0 + ty + j) * cols + c0 + tx];
  __syncthreads();
#pragma unroll
  for (int j = 0; j < 32; j += 8)
    oute[(size_t)(c0 + ty + j) * rows + r0 + tx] = f2bf(t[tx][ty + j]);
}

// ---------------- router: logits, top-2, softmax ----------------
__global__ void k_router(const float* __restrict__ x, const float* __restrict__ wg,
                         const float* __restrict__ bg, int* __restrict__ tidx,
                         float* __restrict__ tgate, int* __restrict__ cnt) {
  int wid = threadIdx.x >> 6, lane = threadIdx.x & 63;
  int t = blockIdx.x * 4 + wid;
  float acc[E_NUM];
#pragma unroll
  for (int e = 0; e < E_NUM; e++) acc[e] = 0.f;
  const float* xr = x + (size_t)t * D_DIM;
  for (int i = lane; i < D_DIM; i += 64) {
    float xv = xr[i];
#pragma unroll
    for (int e = 0; e < E_NUM; e++) acc[e] += xv * wg[e * D_DIM + i];
  }
#pragma unroll
  for (int e = 0; e < E_NUM; e++) {
#pragma unroll
    for (int off = 32; off; off >>= 1) acc[e] += __shfl_xor(acc[e], off);
  }
  if (lane == 0) {
    float v[E_NUM];
#pragma unroll
    for (int e = 0; e < E_NUM; e++) v[e] = acc[e] + bg[e];
    int i0 = 0; float v0 = v[0];
#pragma unroll
    for (int e = 1; e < E_NUM; e++) if (v[e] > v0) { v0 = v[e]; i0 = e; }
    int i1 = -1; float v1 = -1e30f;
#pragma unroll
    for (int e = 0; e < E_NUM; e++) if (e != i0 && v[e] > v1) { v1 = v[e]; i1 = e; }
    float g0 = 1.f / (1.f + expf(v1 - v0));
    float g1 = 1.f - g0;
    tidx[2 * t] = i0; tidx[2 * t + 1] = i1;
    tgate[2 * t] = g0; tgate[2 * t + 1] = g1;
    atomicAdd(cnt + i0, 1);
    atomicAdd(cnt + i1, 1);
  }
}

__global__ void k_prefix(const int* __restrict__ cnt, int* __restrict__ eoff,
                         int* __restrict__ cursor) {
  if (threadIdx.x == 0) {
    int a = 0;
    for (int e = 0; e < E_NUM; e++) { eoff[e] = a; cursor[e] = a; a += cnt[e]; }
    eoff[E_NUM] = a;
  }
}

__global__ void k_scatter(const int* __restrict__ tidx, const float* __restrict__ tgate,
                          int* __restrict__ cursor, int* __restrict__ ptok,
                          float* __restrict__ pgate) {
  int t = blockIdx.x * 256 + threadIdx.x;
#pragma unroll
  for (int k = 0; k < 2; k++) {
    int e = tidx[2 * t + k];
    int p = atomicAdd(cursor + e, 1);
    ptok[p] = t;
    pgate[p] = tgate[2 * t + k];
  }
}

// ------------- grouped GEMM, 256x256 tile, BK=64, counted vmcnt -------------
// LDS per buf per operand: [256 rows][64 bf16] = 128 B rows of 8x16B segs,
// XOR-swizzled: slot[row][s] = data[row][ s ^ (row&7) ]  (T2 recipe).
// Realized via pre-swizzled GLOBAL source (gload_lds dest linear, rule #21).
// Pipeline: 2 K-tiles in flight; per tile: vmcnt(8) -> frag ds_reads ->
// lgkmcnt(0)+barrier (WAR) -> STAGE(tile+2) -> setprio(1) 64 MFMA setprio(0).
// MODE 1: A = xb gathered via ptok, out = relu(A@B^T + b1) -> Hbuf (bf16)
// MODE 2: A = Hbuf rows direct,   out = (A@B^T + b2*(kc==0))*gate atomicAdd
template <int KDIM, int NDIM, int MODE, int KSPLIT>
__global__ __launch_bounds__(512, 1) void k_gemm(
    const unsigned short* __restrict__ A, const unsigned short* __restrict__ Bt,
    const float* __restrict__ bias, const int* __restrict__ eoff,
    const int* __restrict__ ptok, const float* __restrict__ pgate,
    unsigned short* __restrict__ Hout, float* __restrict__ Out) {
  constexpr int NT = NDIM / 256;
  constexpr int MT_MAX = NPAIR / 256;
  constexpr int KLEN = KDIM / KSPLIT;
  int nwg = gridDim.x;
  int bid = blockIdx.x;
  int tile = (bid & 7) * (nwg >> 3) + (bid >> 3);  // XCD chunk swizzle (nwg%8==0)
  int e = tile / (MT_MAX * NT * KSPLIT);
  int rem = tile % (MT_MAX * NT * KSPLIT);
  int mt = rem / (NT * KSPLIT);
  int rem2 = rem % (NT * KSPLIT);
  int nt = rem2 / KSPLIT;
  int kc = rem2 % KSPLIT;
  int off = eoff[e];
  int cnt = eoff[e + 1] - off;
  int m0 = mt * 256;
  if (m0 >= cnt) return;
  int kbase = kc * KLEN;

  // [buf][A=0/B=1][256][64] bf16 = 128 KiB
  __shared__ unsigned short lds_raw[2 * 2 * 256 * 64];
#define LDSOP(b, op) (lds_raw + ((b) * 2 + (op)) * 16384)

  int tid = threadIdx.x;
  int w = tid >> 6, lane = tid & 63;
  int wm = w >> 2, wn = w & 3;  // 2 x 4 wave grid; per-wave output 128 x 64

  // Staging geometry: issue c in 0..3 per operand; LDS short-offset =
  // c*4096 + w*512 + lane*8shorts... (bytes: c*8192 + w*1024 + lane*16).
  // row = c*64 + w*8 + (lane>>3), slotseg = lane&7, row&7 = (lane>>3)&7.
  // Pre-swizzled global seg = slotseg ^ (row&7):
  int srcseg = (lane & 7) ^ ((lane >> 3) & 7);
  const unsigned short* aSrc[4];
  const unsigned short* bSrc[4];
#pragma unroll
  for (int c = 0; c < 4; c++) {
    int rA = c * 64 + w * 8 + (lane >> 3);  // row within 256-row tile
    int arow = m0 + rA;
    int ar = (arow < cnt) ? arow : (cnt - 1);
    size_t grow;
    if (MODE == 1) grow = (size_t)ptok[off + ar];
    else grow = (size_t)(off + ar);
    aSrc[c] = A + grow * KDIM + srcseg * 8;
    int nrow = nt * 256 + rA;
    bSrc[c] = Bt + (size_t)e * NDIM * KDIM + (size_t)nrow * KDIM + srcseg * 8;
  }

  // Fragment reads: row = base + (lane&15); wanted seg = ks*4 + (lane>>4);
  // slot seg' = wanted ^ (row&7) = wanted ^ (lane&7).
  int segp0 = (lane >> 4) ^ (lane & 7);
  int segp1 = segp0 ^ 4;
  f32x4 acc[8][4] = {};

#define STAGE(buf, k0)                                               \
  {                                                                  \
    _Pragma("unroll")                                                \
    for (int c = 0; c < 4; c++) {                                    \
      gload16(aSrc[c] + (k0), LDSOP(buf, 0) + c * 4096 + w * 512);   \
      gload16(bSrc[c] + (k0), LDSOP(buf, 1) + c * 4096 + w * 512);   \
    }                                                                \
  }

#define FRAG_LOADS(buf)                                              \
  bf16x8 aF[8][2], bF[4][2];                                         \
  {                                                                  \
    const unsigned short* pa = LDSOP(buf, 0);                        \
    const unsigned short* pb = LDSOP(buf, 1);                        \
    _Pragma("unroll")                                                \
    for (int m = 0; m < 8; m++) {                                    \
      int row = wm * 128 + m * 16 + (lane & 15);                     \
      aF[m][0] = *(const bf16x8*)&pa[row * 64 + segp0 * 8];          \
      aF[m][1] = *(const bf16x8*)&pa[row * 64 + segp1 * 8];          \
    }                                                                \
    _Pragma("unroll")                                                \
    for (int n = 0; n < 4; n++) {                                    \
      int row = wn * 64 + n * 16 + (lane & 15);                      \
      bF[n][0] = *(const bf16x8*)&pb[row * 64 + segp0 * 8];          \
      bF[n][1] = *(const bf16x8*)&pb[row * 64 + segp1 * 8];          \
    }                                                                \
  }

#define MFMA_ALL()                                                   \
  __builtin_amdgcn_s_setprio(1);                                     \
  _Pragma("unroll")                                                  \
  for (int ks = 0; ks < 2; ks++)                                     \
    _Pragma("unroll")                                                \
    for (int m = 0; m < 8; m++)                                      \
      _Pragma("unroll")                                              \
      for (int n = 0; n < 4; n++)                                    \
        acc[m][n] = __builtin_amdgcn_mfma_f32_16x16x32_bf16(         \
            aF[m][ks], bF[n][ks], acc[m][n], 0, 0, 0);               \
  __builtin_amdgcn_s_setprio(0);

  // prologue: 2 K-tiles in flight (8 loads each per thread)
  STAGE(0, kbase);
  STAGE(1, kbase + 64);

#pragma unroll 1
  for (int kk = 0; kk < KLEN - 128; kk += 128) {
    {
      WAIT_VM8(); BARRIER();          // buf0's 8 loads done (buf1's in flight)
      FRAG_LOADS(0);
      WAIT_LGKM0(); BARRIER();        // all waves done reading buf0
      STAGE(0, kbase + kk + 128);     // overwrite buf0 with tile kt+2
      MFMA_ALL();
    }
    {
      WAIT_VM8(); BARRIER();          // buf1's 8 loads done
      FRAG_LOADS(1);
      WAIT_LGKM0(); BARRIER();
      STAGE(1, kbase + kk + 192);
      MFMA_ALL();
    }
  }
  // epilogue: last two tiles, no staging
  {
    WAIT_VM8(); BARRIER();
    FRAG_LOADS(0);
    MFMA_ALL();
  }
  {
    WAIT_VM0(); BARRIER();
    FRAG_LOADS(1);
    MFMA_ALL();
  }

#undef STAGE
#undef FRAG_LOADS
#undef MFMA_ALL
#undef LDSOP

  // epilogue: C/D map col=lane&15, row=(lane>>4)*4+r
#pragma unroll
  for (int m = 0; m < 8; m++) {
    int lrowb = wm * 128 + m * 16 + (lane >> 4) * 4;
#pragma unroll
    for (int r = 0; r < 4; r++) {
      int arow = m0 + lrowb + r;
      if (arow < cnt) {
        if constexpr (MODE == 1) {
          size_t rowbase = (size_t)(off + arow) * NDIM;
#pragma unroll
          for (int n = 0; n < 4; n++) {
            int col = nt * 256 + wn * 64 + n * 16 + (lane & 15);
            float v = acc[m][n][r] + bias[e * NDIM + col];
            v = v > 0.f ? v : 0.f;
            Hout[rowbase + col] = f2bf(v);
          }
        } else {
          int tok = ptok[off + arow];
          float g = pgate[off + arow];
#pragma unroll
          for (int n = 0; n < 4; n++) {
            int col = nt * 256 + wn * 64 + n * 16 + (lane & 15);
            float b = (kc == 0) ? bias[e * NDIM + col] : 0.f;
            float v = (acc[m][n][r] + b) * g;
            atomicAdd(Out + (size_t)tok * D_DIM + col, v);
          }
        }
      }
    }
  }
}

extern "C" void kernel_launch(void* const* d_in, const int* in_sizes, int n_in,
                              void* d_out, int out_size, void* d_ws, size_t ws_size,
                              hipStream_t stream) {
  const float* x  = (const float*)d_in[0];
  const float* wg = (const float*)d_in[1];
  const float* bg = (const float*)d_in[2];
  const float* w1 = (const float*)d_in[3];
  const float* b1 = (const float*)d_in[4];
  const float* w2 = (const float*)d_in[5];
  const float* b2 = (const float*)d_in[6];
  float* out = (float*)d_out;

  char* ws = (char*)d_ws;
  unsigned short* xb = (unsigned short*)ws;   ws += (size_t)B_TOK * D_DIM * 2;
  unsigned short* w1t = (unsigned short*)ws;  ws += (size_t)E_NUM * D_DIM * H_DIM * 2;
  unsigned short* w2t = (unsigned short*)ws;  ws += (size_t)E_NUM * D_DIM * H_DIM * 2;
  unsigned short* Hbuf = (unsigned short*)ws; ws += (size_t)NPAIR * H_DIM * 2;
  int* tidx = (int*)ws;    ws += (size_t)NPAIR * 4;
  float* tgate = (float*)ws; ws += (size_t)NPAIR * 4;
  int* ptok = (int*)ws;    ws += (size_t)NPAIR * 4;
  float* pgate = (float*)ws; ws += (size_t)NPAIR * 4;
  int* meta = (int*)ws;  // cnt[8] | eoff[9] | cursor[8]
  int* cnt = meta;
  int* eoff = meta + 8;
  int* cursor = meta + 17;

  hipMemsetAsync(meta, 0, 32 * sizeof(int), stream);
  hipMemsetAsync(out, 0, (size_t)out_size * sizeof(float), stream);

  k_convert_x<<<(B_TOK * D_DIM) / 1024, 256, 0, stream>>>(x, xb);
  dim3 tb(32, 8);
  k_transpose_bf16<<<dim3(H_DIM / 32, D_DIM / 32, E_NUM), tb, 0, stream>>>(w1, w1t, D_DIM, H_DIM);
  k_transpose_bf16<<<dim3(D_DIM / 32, H_DIM / 32, E_NUM), tb, 0, stream>>>(w2, w2t, H_DIM, D_DIM);
  k_router<<<B_TOK / 4, 256, 0, stream>>>(x, wg, bg, tidx, tgate, cnt);
  k_prefix<<<1, 64, 0, stream>>>(cnt, eoff, cursor);
  k_scatter<<<B_TOK / 256, 256, 0, stream>>>(tidx, tgate, cursor, ptok, pgate);
  k_gemm<D_DIM, H_DIM, 1, 1><<<E_NUM * (NPAIR / 256) * (H_DIM / 256), 512, 0, stream>>>(
      xb, w1t, b1, eoff, ptok, pgate, Hbuf, nullptr);
  k_gemm<H_DIM, D_DIM, 2, 2><<<E_NUM * (NPAIR / 256) * (D_DIM / 256) * 2, 512, 0, stream>>>(
      Hbuf, w2t, b2, eoff, ptok, pgate, nullptr, out);
}

// Round 5
// 874.112 us; speedup vs baseline: 1.3765x; 1.3765x over previous
//
#include <hip/hip_runtime.h>
#include <hip/hip_bf16.h>
#include <math.h>

#define B_TOK 8192
#define D_DIM 1024
#define H_DIM 4096
#define E_NUM 8
#define NPAIR (B_TOK * 2)

typedef __bf16 bf16x8 __attribute__((ext_vector_type(8)));
typedef float f32x4 __attribute__((ext_vector_type(4)));
typedef unsigned short us4 __attribute__((ext_vector_type(4)));

__device__ __forceinline__ unsigned short f2bf(float f) {
  union { float f; unsigned u; } v; v.f = f;
  unsigned r = v.u + 0x7FFFu + ((v.u >> 16) & 1u);
  return (unsigned short)(r >> 16);
}

__device__ __forceinline__ void gload16(const void* g, void* l) {
  __builtin_amdgcn_global_load_lds(
      (const __attribute__((address_space(1))) void*)g,
      (__attribute__((address_space(3))) void*)l, 16, 0, 0);
}

#define BARRIER()    asm volatile("s_barrier" ::: "memory")
#define WAIT_VM4()   asm volatile("s_waitcnt vmcnt(4)" ::: "memory")
#define WAIT_VM0()   asm volatile("s_waitcnt vmcnt(0)" ::: "memory")
#define WAIT_LGKM0() asm volatile("s_waitcnt lgkmcnt(0)" ::: "memory")

// ---------------- x fp32 -> bf16 ----------------
__global__ void k_convert_x(const float* __restrict__ x, unsigned short* __restrict__ xb) {
  int i = (blockIdx.x * 256 + threadIdx.x) * 4;
  float4 v = *(const float4*)(x + i);
  us4 o;
  o[0] = f2bf(v.x); o[1] = f2bf(v.y); o[2] = f2bf(v.z); o[3] = f2bf(v.w);
  *(us4*)(xb + i) = o;
}

// -------- (E, rows, cols) fp32 -> (E, cols, rows) bf16 --------
__global__ void k_transpose_bf16(const float* __restrict__ in, unsigned short* __restrict__ out,
                                 int rows, int cols) {
  __shared__ float t[32][33];
  const float* ine = in + (size_t)blockIdx.z * rows * cols;
  unsigned short* oute = out + (size_t)blockIdx.z * rows * cols;
  int c0 = blockIdx.x * 32, r0 = blockIdx.y * 32;
  int tx = threadIdx.x, ty = threadIdx.y;
#pragma unroll
  for (int j = 0; j < 32; j += 8)
    t[ty + j][tx] = ine[(size_t)(r0 + ty + j) * cols + c0 + tx];
  __syncthreads();
#pragma unroll
  for (int j = 0; j < 32; j += 8)
    oute[(size_t)(c0 + ty + j) * rows + r0 + tx] = f2bf(t[tx][ty + j]);
}

// ---------------- router: logits, top-2, softmax ----------------
__global__ void k_router(const float* __restrict__ x, const float* __restrict__ wg,
                         const float* __restrict__ bg, int* __restrict__ tidx,
                         float* __restrict__ tgate, int* __restrict__ cnt) {
  int wid = threadIdx.x >> 6, lane = threadIdx.x & 63;
  int t = blockIdx.x * 4 + wid;
  float acc[E_NUM];
#pragma unroll
  for (int e = 0; e < E_NUM; e++) acc[e] = 0.f;
  const float* xr = x + (size_t)t * D_DIM;
  for (int i = lane; i < D_DIM; i += 64) {
    float xv = xr[i];
#pragma unroll
    for (int e = 0; e < E_NUM; e++) acc[e] += xv * wg[e * D_DIM + i];
  }
#pragma unroll
  for (int e = 0; e < E_NUM; e++) {
#pragma unroll
    for (int off = 32; off; off >>= 1) acc[e] += __shfl_xor(acc[e], off);
  }
  if (lane == 0) {
    float v[E_NUM];
#pragma unroll
    for (int e = 0; e < E_NUM; e++) v[e] = acc[e] + bg[e];
    int i0 = 0; float v0 = v[0];
#pragma unroll
    for (int e = 1; e < E_NUM; e++) if (v[e] > v0) { v0 = v[e]; i0 = e; }
    int i1 = -1; float v1 = -1e30f;
#pragma unroll
    for (int e = 0; e < E_NUM; e++) if (e != i0 && v[e] > v1) { v1 = v[e]; i1 = e; }
    float g0 = 1.f / (1.f + expf(v1 - v0));
    float g1 = 1.f - g0;
    tidx[2 * t] = i0; tidx[2 * t + 1] = i1;
    tgate[2 * t] = g0; tgate[2 * t + 1] = g1;
    atomicAdd(cnt + i0, 1);
    atomicAdd(cnt + i1, 1);
  }
}

__global__ void k_prefix(const int* __restrict__ cnt, int* __restrict__ eoff,
                         int* __restrict__ cursor) {
  if (threadIdx.x == 0) {
    int a = 0;
    for (int e = 0; e < E_NUM; e++) { eoff[e] = a; cursor[e] = a; a += cnt[e]; }
    eoff[E_NUM] = a;
  }
}

__global__ void k_scatter(const int* __restrict__ tidx, const float* __restrict__ tgate,
                          int* __restrict__ cursor, int* __restrict__ ptok,
                          float* __restrict__ pgate) {
  int t = blockIdx.x * 256 + threadIdx.x;
#pragma unroll
  for (int k = 0; k < 2; k++) {
    int e = tidx[2 * t + k];
    int p = atomicAdd(cursor + e, 1);
    ptok[p] = t;
    pgate[p] = tgate[2 * t + k];
  }
}

// ---- grouped GEMM, 256x256 tile, BK=32 (R3 geometry), counted vmcnt (T4) ---
// LDS per buf per operand: [256 rows][32 bf16] = 64B rows, 4x16B segs,
// swizzled slot[row][s] = data[row][s ^ ((row>>1)&3)] via pre-swizzled global
// source (gload_lds dest linear, rule #21). Verified 0 bank conflicts (R3).
// Pipeline: 2 K-tiles in flight; per tile: vmcnt(4) -> barrier -> frag
// ds_reads -> lgkmcnt(0) -> barrier (WAR) -> STAGE(t+2) -> setprio MFMAx32.
// MODE 1: A = xb gathered via ptok, out = relu(A@B^T + b1) -> Hbuf (bf16)
// MODE 2: A = Hbuf rows direct,   out = (A@B^T + b2)*gate atomicAdd-> Out
template <int KDIM, int NDIM, int MODE>
__global__ __launch_bounds__(512, 1) void k_gemm(
    const unsigned short* __restrict__ A, const unsigned short* __restrict__ Bt,
    const float* __restrict__ bias, const int* __restrict__ eoff,
    const int* __restrict__ ptok, const float* __restrict__ pgate,
    unsigned short* __restrict__ Hout, float* __restrict__ Out) {
  constexpr int NT = NDIM / 256;
  constexpr int MT_MAX = NPAIR / 256;
  int nwg = gridDim.x;
  int bid = blockIdx.x;
  int tile = (bid & 7) * (nwg >> 3) + (bid >> 3);  // XCD chunk swizzle (nwg%8==0)
  int e = tile / (MT_MAX * NT);
  int rem = tile - e * (MT_MAX * NT);
  int mt = rem / NT;
  int nt = rem - mt * NT;
  int off = eoff[e];
  int cnt = eoff[e + 1] - off;
  int m0 = mt * 256;
  if (m0 >= cnt) return;

  __shared__ unsigned short lds[2][2][256 * 32];  // [buf][A/B][row][32 shorts]

  int tid = threadIdx.x;
  int w = tid >> 6, lane = tid & 63;
  int wm = w >> 2, wn = w & 3;  // 2 x 4 wave grid, each wave: 128 x 64 output

  // staging: chunk q = w*2+c covers rows q*16..q*16+15; lane -> row q*16+(lane>>2),
  // LDS slot seg (lane&3). Global source seg pre-swizzled: (lane&3)^((lane>>3)&3).
  int sseg = (lane & 3) ^ ((lane >> 3) & 3);
  const unsigned short* aSrc[2];
  const unsigned short* bSrc[2];
#pragma unroll
  for (int c = 0; c < 2; c++) {
    int q = w * 2 + c;
    int lrow = q * 16 + (lane >> 2);
    int arow = m0 + lrow;
    int ar = (arow < cnt) ? arow : (cnt - 1);
    size_t grow;
    if (MODE == 1) grow = (size_t)ptok[off + ar];
    else grow = (size_t)(off + ar);
    aSrc[c] = A + grow * KDIM + sseg * 8;
    int nrow = nt * 256 + q * 16 + (lane >> 2);
    bSrc[c] = Bt + (size_t)e * NDIM * KDIM + (size_t)nrow * KDIM + sseg * 8;
  }

  // fragment reads: row = base + (lane&15); wanted seg g = lane>>4;
  // read slot seg' = g ^ ((row>>1)&3) = (lane>>4) ^ ((lane>>1)&3) -- per-thread const.
  int segp = (lane >> 4) ^ ((lane >> 1) & 3);
  f32x4 acc[8][4] = {};

#define STAGE(buf, k0)                                          \
  {                                                             \
    _Pragma("unroll")                                           \
    for (int c = 0; c < 2; c++) {                               \
      int q = w * 2 + c;                                        \
      gload16(aSrc[c] + (k0), &lds[buf][0][q * 512]);           \
      gload16(bSrc[c] + (k0), &lds[buf][1][q * 512]);           \
    }                                                           \
  }

#define FRAG_READ(buf)                                                      \
    _Pragma("unroll")                                                       \
    for (int m = 0; m < 8; m++) {                                           \
      int row = wm * 128 + m * 16 + (lane & 15);                            \
      aF[m] = *(const bf16x8*)&lds[buf][0][row * 32 + segp * 8];            \
    }                                                                       \
    _Pragma("unroll")                                                       \
    for (int n = 0; n < 4; n++) {                                           \
      int row = wn * 64 + n * 16 + (lane & 15);                             \
      bF[n] = *(const bf16x8*)&lds[buf][1][row * 32 + segp * 8];            \
    }

#define MFMA_ALL()                                                          \
    __builtin_amdgcn_s_setprio(1);                                          \
    _Pragma("unroll")                                                       \
    for (int m = 0; m < 8; m++)                                             \
      _Pragma("unroll")                                                     \
      for (int n = 0; n < 4; n++)                                           \
        acc[m][n] =                                                         \
            __builtin_amdgcn_mfma_f32_16x16x32_bf16(aF[m], bF[n], acc[m][n], 0, 0, 0); \
    __builtin_amdgcn_s_setprio(0);

  // prologue: 2 K-tiles in flight (4 loads each per thread)
  STAGE(0, 0);
  STAGE(1, 32);

#pragma unroll 1
  for (int k0 = 0; k0 < KDIM - 64; k0 += 64) {
    {
      WAIT_VM4(); BARRIER();        // buf0's 4 loads landed (buf1's in flight)
      bf16x8 aF[8], bF[4];
      FRAG_READ(0);
      WAIT_LGKM0(); BARRIER();      // all waves done reading buf0
      STAGE(0, k0 + 64);            // refill buf0 with tile t+2
      MFMA_ALL();
    }
    {
      WAIT_VM4(); BARRIER();        // buf1's 4 loads landed
      bf16x8 aF[8], bF[4];
      FRAG_READ(1);
      WAIT_LGKM0(); BARRIER();
      STAGE(1, k0 + 96);
      MFMA_ALL();
    }
  }
  // tail: last two tiles, no further staging
  {
    WAIT_VM4(); BARRIER();
    bf16x8 aF[8], bF[4];
    FRAG_READ(0);
    MFMA_ALL();
  }
  {
    WAIT_VM0(); BARRIER();
    bf16x8 aF[8], bF[4];
    FRAG_READ(1);
    MFMA_ALL();
  }

#undef STAGE
#undef FRAG_READ
#undef MFMA_ALL

  // epilogue: C/D map col=lane&15, row=(lane>>4)*4+r
#pragma unroll
  for (int m = 0; m < 8; m++) {
    int lrowb = wm * 128 + m * 16 + (lane >> 4) * 4;
#pragma unroll
    for (int r = 0; r < 4; r++) {
      int arow = m0 + lrowb + r;
      if (arow < cnt) {
        if constexpr (MODE == 1) {
          size_t rowbase = (size_t)(off + arow) * NDIM;
#pragma unroll
          for (int n = 0; n < 4; n++) {
            int col = nt * 256 + wn * 64 + n * 16 + (lane & 15);
            float v = acc[m][n][r] + bias[e * NDIM + col];
            v = v > 0.f ? v : 0.f;
            Hout[rowbase + col] = f2bf(v);
          }
        } else {
          int tok = ptok[off + arow];
          float g = pgate[off + arow];
#pragma unroll
          for (int n = 0; n < 4; n++) {
            int col = nt * 256 + wn * 64 + n * 16 + (lane & 15);
            float v = (acc[m][n][r] + bias[e * NDIM + col]) * g;
            atomicAdd(Out + (size_t)tok * D_DIM + col, v);
          }
        }
      }
    }
  }
}

extern "C" void kernel_launch(void* const* d_in, const int* in_sizes, int n_in,
                              void* d_out, int out_size, void* d_ws, size_t ws_size,
                              hipStream_t stream) {
  const float* x  = (const float*)d_in[0];
  const float* wg = (const float*)d_in[1];
  const float* bg = (const float*)d_in[2];
  const float* w1 = (const float*)d_in[3];
  const float* b1 = (const float*)d_in[4];
  const float* w2 = (const float*)d_in[5];
  const float* b2 = (const float*)d_in[6];
  float* out = (float*)d_out;

  char* ws = (char*)d_ws;
  unsigned short* xb = (unsigned short*)ws;   ws += (size_t)B_TOK * D_DIM * 2;
  unsigned short* w1t = (unsigned short*)ws;  ws += (size_t)E_NUM * D_DIM * H_DIM * 2;
  unsigned short* w2t = (unsigned short*)ws;  ws += (size_t)E_NUM * D_DIM * H_DIM * 2;
  unsigned short* Hbuf = (unsigned short*)ws; ws += (size_t)NPAIR * H_DIM * 2;
  int* tidx = (int*)ws;    ws += (size_t)NPAIR * 4;
  float* tgate = (float*)ws; ws += (size_t)NPAIR * 4;
  int* ptok = (int*)ws;    ws += (size_t)NPAIR * 4;
  float* pgate = (float*)ws; ws += (size_t)NPAIR * 4;
  int* meta = (int*)ws;  // cnt[8] | eoff[9] | cursor[8]
  int* cnt = meta;
  int* eoff = meta + 8;
  int* cursor = meta + 17;

  hipMemsetAsync(meta, 0, 32 * sizeof(int), stream);
  hipMemsetAsync(out, 0, (size_t)out_size * sizeof(float), stream);

  k_convert_x<<<(B_TOK * D_DIM) / 1024, 256, 0, stream>>>(x, xb);
  dim3 tb(32, 8);
  k_transpose_bf16<<<dim3(H_DIM / 32, D_DIM / 32, E_NUM), tb, 0, stream>>>(w1, w1t, D_DIM, H_DIM);
  k_transpose_bf16<<<dim3(D_DIM / 32, H_DIM / 32, E_NUM), tb, 0, stream>>>(w2, w2t, H_DIM, D_DIM);
  k_router<<<B_TOK / 4, 256, 0, stream>>>(x, wg, bg, tidx, tgate, cnt);
  k_prefix<<<1, 64, 0, stream>>>(cnt, eoff, cursor);
  k_scatter<<<B_TOK / 256, 256, 0, stream>>>(tidx, tgate, cursor, ptok, pgate);
  k_gemm<D_DIM, H_DIM, 1><<<E_NUM * (NPAIR / 256) * (H_DIM / 256), 512, 0, stream>>>(
      xb, w1t, b1, eoff, ptok, pgate, Hbuf, nullptr);
  k_gemm<H_DIM, D_DIM, 2><<<E_NUM * (NPAIR / 256) * (D_DIM / 256), 512, 0, stream>>>(
      Hbuf, w2t, b2, eoff, ptok, pgate, nullptr, out);
}

// Round 6
// 860.215 us; speedup vs baseline: 1.3987x; 1.0162x over previous
//
#include <hip/hip_runtime.h>
#include <hip/hip_bf16.h>
#include <math.h>

#define B_TOK 8192
#define D_DIM 1024
#define H_DIM 4096
#define E_NUM 8
#define NPAIR (B_TOK * 2)

typedef __bf16 bf16x8 __attribute__((ext_vector_type(8)));
typedef float f32x4 __attribute__((ext_vector_type(4)));
typedef unsigned short us4 __attribute__((ext_vector_type(4)));

__device__ __forceinline__ unsigned short f2bf(float f) {
  union { float f; unsigned u; } v; v.f = f;
  unsigned r = v.u + 0x7FFFu + ((v.u >> 16) & 1u);
  return (unsigned short)(r >> 16);
}

__device__ __forceinline__ void gload16(const void* g, void* l) {
  __builtin_amdgcn_global_load_lds(
      (const __attribute__((address_space(1))) void*)g,
      (__attribute__((address_space(3))) void*)l, 16, 0, 0);
}

#define VM4 asm volatile("s_waitcnt vmcnt(4)" ::: "memory")
#define VM2 asm volatile("s_waitcnt vmcnt(2)" ::: "memory")
#define VM0 asm volatile("s_waitcnt vmcnt(0)" ::: "memory")
#define NOPW ((void)0)

// ---------------- x fp32 -> bf16 ----------------
__global__ void k_convert_x(const float* __restrict__ x, unsigned short* __restrict__ xb) {
  int i = (blockIdx.x * 256 + threadIdx.x) * 4;
  float4 v = *(const float4*)(x + i);
  us4 o;
  o[0] = f2bf(v.x); o[1] = f2bf(v.y); o[2] = f2bf(v.z); o[3] = f2bf(v.w);
  *(us4*)(xb + i) = o;
}

// -------- (E, rows, cols) fp32 -> (E, cols, rows) bf16 --------
__global__ void k_transpose_bf16(const float* __restrict__ in, unsigned short* __restrict__ out,
                                 int rows, int cols) {
  __shared__ float t[32][33];
  const float* ine = in + (size_t)blockIdx.z * rows * cols;
  unsigned short* oute = out + (size_t)blockIdx.z * rows * cols;
  int c0 = blockIdx.x * 32, r0 = blockIdx.y * 32;
  int tx = threadIdx.x, ty = threadIdx.y;
#pragma unroll
  for (int j = 0; j < 32; j += 8)
    t[ty + j][tx] = ine[(size_t)(r0 + ty + j) * cols + c0 + tx];
  __syncthreads();
#pragma unroll
  for (int j = 0; j < 32; j += 8)
    oute[(size_t)(c0 + ty + j) * rows + r0 + tx] = f2bf(t[tx][ty + j]);
}

// ---------------- router: logits, top-2, softmax ----------------
__global__ void k_router(const float* __restrict__ x, const float* __restrict__ wg,
                         const float* __restrict__ bg, int* __restrict__ tidx,
                         float* __restrict__ tgate, int* __restrict__ cnt) {
  int wid = threadIdx.x >> 6, lane = threadIdx.x & 63;
  int t = blockIdx.x * 4 + wid;
  float acc[E_NUM];
#pragma unroll
  for (int e = 0; e < E_NUM; e++) acc[e] = 0.f;
  const float* xr = x + (size_t)t * D_DIM;
  for (int i = lane; i < D_DIM; i += 64) {
    float xv = xr[i];
#pragma unroll
    for (int e = 0; e < E_NUM; e++) acc[e] += xv * wg[e * D_DIM + i];
  }
#pragma unroll
  for (int e = 0; e < E_NUM; e++) {
#pragma unroll
    for (int off = 32; off; off >>= 1) acc[e] += __shfl_xor(acc[e], off);
  }
  if (lane == 0) {
    float v[E_NUM];
#pragma unroll
    for (int e = 0; e < E_NUM; e++) v[e] = acc[e] + bg[e];
    int i0 = 0; float v0 = v[0];
#pragma unroll
    for (int e = 1; e < E_NUM; e++) if (v[e] > v0) { v0 = v[e]; i0 = e; }
    int i1 = -1; float v1 = -1e30f;
#pragma unroll
    for (int e = 0; e < E_NUM; e++) if (e != i0 && v[e] > v1) { v1 = v[e]; i1 = e; }
    float g0 = 1.f / (1.f + expf(v1 - v0));
    float g1 = 1.f - g0;
    tidx[2 * t] = i0; tidx[2 * t + 1] = i1;
    tgate[2 * t] = g0; tgate[2 * t + 1] = g1;
    atomicAdd(cnt + i0, 1);
    atomicAdd(cnt + i1, 1);
  }
}

__global__ void k_prefix(const int* __restrict__ cnt, int* __restrict__ eoff,
                         int* __restrict__ cursor) {
  if (threadIdx.x == 0) {
    int a = 0;
    for (int e = 0; e < E_NUM; e++) { eoff[e] = a; cursor[e] = a; a += cnt[e]; }
    eoff[E_NUM] = a;
  }
}

__global__ void k_scatter(const int* __restrict__ tidx, const float* __restrict__ tgate,
                          int* __restrict__ cursor, int* __restrict__ ptok,
                          float* __restrict__ pgate) {
  int t = blockIdx.x * 256 + threadIdx.x;
#pragma unroll
  for (int k = 0; k < 2; k++) {
    int e = tidx[2 * t + k];
    int p = atomicAdd(cursor + e, 1);
    ptok[p] = t;
    pgate[p] = tgate[2 * t + k];
  }
}

// ------ grouped GEMM, 256x256 tile, BK=64, 8-phase (4/K-tile) schedule ------
// LDS [buf][A=0/B=1][256 rows][64 bf16]: 128B rows, 8x16B segs, XOR-swizzled
// slot[row][s] = data[row][s ^ (row&7)] via pre-swizzled global source
// (gload_lds dest linear, rule #21). R4 measured 0 bank conflicts on this.
// Phase p (0..3) of K-tile t (read buf t&1):
//   ds_read aF m={2p,2p+1} both ks (+ all bF[4][2] in p0)
//   stage 1 pair of tile t+1 into buf (t+1)&1   (order B01,B23,A02,A13)
//   counted vmcnt: vm4 @p1 (A13(t) landed before p2 reads), vm2 @p3
//     (B+A02(t+1) landed before next tile's p0 reads)  -- never 0 in loop
//   barrier; lgkm(0)+sched_barrier; setprio(1); 16 MFMA; setprio(0); barrier
// MODE 1: A = xb gathered via ptok, out = relu(A@B^T + b1) -> Hbuf (bf16)
// MODE 2: A = Hbuf rows direct,   out = (A@B^T + b2)*gate atomicAdd-> Out
template <int KDIM, int NDIM, int MODE>
__global__ __launch_bounds__(512, 1) void k_gemm(
    const unsigned short* __restrict__ A, const unsigned short* __restrict__ Bt,
    const float* __restrict__ bias, const int* __restrict__ eoff,
    const int* __restrict__ ptok, const float* __restrict__ pgate,
    unsigned short* __restrict__ Hout, float* __restrict__ Out) {
  constexpr int NT = NDIM / 256;
  constexpr int MT_MAX = NPAIR / 256;
  int nwg = gridDim.x;
  int bid = blockIdx.x;
  int tile = (bid & 7) * (nwg >> 3) + (bid >> 3);  // XCD chunk swizzle (nwg%8==0)
  int e = tile / (MT_MAX * NT);
  int rem = tile - e * (MT_MAX * NT);
  int mt = rem / NT;
  int nt = rem - mt * NT;
  int off = eoff[e];
  int cnt = eoff[e + 1] - off;
  int m0 = mt * 256;
  if (m0 >= cnt) return;  // block-uniform

  __shared__ unsigned short lds[2][2][256 * 64];  // 128 KiB

  int tid = threadIdx.x;
  int w = tid >> 6, lane = tid & 63;
  int wm = w >> 2, wn = w & 3;  // 2x4 wave grid; per-wave output 128x64

  // Staging: chunk c rows c*64 + w*8 + (lane>>3); slot seg lane&7; LDS short
  // offset c*4096 + w*512 + lane*8. Pre-swizzled global seg:
  int srcseg = (lane & 7) ^ ((lane >> 3) & 7);
  const unsigned short* aSrc[4];
  const unsigned short* bSrc[4];
#pragma unroll
  for (int c = 0; c < 4; c++) {
    int rA = c * 64 + w * 8 + (lane >> 3);
    int arow = m0 + rA;
    int ar = (arow < cnt) ? arow : (cnt - 1);
    size_t grow;
    if (MODE == 1) grow = (size_t)ptok[off + ar];
    else grow = (size_t)(off + ar);
    aSrc[c] = A + grow * KDIM + srcseg * 8;
    int nrow = nt * 256 + rA;
    bSrc[c] = Bt + (size_t)e * NDIM * KDIM + (size_t)nrow * KDIM + srcseg * 8;
  }

  // Frag reads: row&7 == lane&7; wanted seg ks*4+(lane>>4); slot = wanted^(lane&7)
  int segp0 = (lane >> 4) ^ (lane & 7);
  int segp1 = segp0 ^ 4;
  f32x4 acc[8][4] = {};

#define STG_B01(bb, k0) { gload16(bSrc[0] + (k0), &lds[bb][1][0 * 4096 + w * 512]); \
                          gload16(bSrc[1] + (k0), &lds[bb][1][1 * 4096 + w * 512]); }
#define STG_B23(bb, k0) { gload16(bSrc[2] + (k0), &lds[bb][1][2 * 4096 + w * 512]); \
                          gload16(bSrc[3] + (k0), &lds[bb][1][3 * 4096 + w * 512]); }
#define STG_A02(bb, k0) { gload16(aSrc[0] + (k0), &lds[bb][0][0 * 4096 + w * 512]); \
                          gload16(aSrc[2] + (k0), &lds[bb][0][2 * 4096 + w * 512]); }
#define STG_A13(bb, k0) { gload16(aSrc[1] + (k0), &lds[bb][0][1 * 4096 + w * 512]); \
                          gload16(aSrc[3] + (k0), &lds[bb][0][3 * 4096 + w * 512]); }

#define PH(bb, p, STGCODE, WAITCODE)                                         \
  {                                                                          \
    bf16x8 aF[2][2];                                                         \
    if ((p) == 0) {                                                          \
      _Pragma("unroll") for (int n = 0; n < 4; n++) {                        \
        int row = wn * 64 + n * 16 + (lane & 15);                            \
        bF[n][0] = *(const bf16x8*)&lds[bb][1][row * 64 + segp0 * 8];        \
        bF[n][1] = *(const bf16x8*)&lds[bb][1][row * 64 + segp1 * 8];        \
      }                                                                      \
    }                                                                        \
    _Pragma("unroll") for (int mm = 0; mm < 2; mm++) {                       \
      int row = wm * 128 + ((p) * 2 + mm) * 16 + (lane & 15);                \
      aF[mm][0] = *(const bf16x8*)&lds[bb][0][row * 64 + segp0 * 8];         \
      aF[mm][1] = *(const bf16x8*)&lds[bb][0][row * 64 + segp1 * 8];         \
    }                                                                        \
    STGCODE;                                                                 \
    WAITCODE;                                                                \
    __builtin_amdgcn_s_barrier();                                            \
    asm volatile("s_waitcnt lgkmcnt(0)" ::: "memory");                       \
    __builtin_amdgcn_sched_barrier(0);                                       \
    __builtin_amdgcn_s_setprio(1);                                           \
    _Pragma("unroll") for (int ks = 0; ks < 2; ks++)                         \
      _Pragma("unroll") for (int mm = 0; mm < 2; mm++)                       \
        _Pragma("unroll") for (int n = 0; n < 4; n++)                        \
          acc[(p) * 2 + mm][n] = __builtin_amdgcn_mfma_f32_16x16x32_bf16(    \
              aF[mm][ks], bF[n][ks], acc[(p) * 2 + mm][n], 0, 0, 0);         \
    __builtin_amdgcn_s_setprio(0);                                           \
    __builtin_amdgcn_s_barrier();                                            \
  }

#define TILE(bb, STG0, STG1, STG2, STG3, W1, W3)                             \
  {                                                                          \
    bf16x8 bF[4][2];                                                         \
    PH(bb, 0, STG0, NOPW);                                                   \
    PH(bb, 1, STG1, W1);                                                     \
    PH(bb, 2, STG2, NOPW);                                                   \
    PH(bb, 3, STG3, W3);                                                     \
  }

  // prologue: stage tile 0 into buf0; wait all but last pair; barrier
  STG_B01(0, 0); STG_B23(0, 0); STG_A02(0, 0); STG_A13(0, 0);
  VM2;
  __builtin_amdgcn_s_barrier();

  constexpr int NKT = KDIM / 64;
#pragma unroll 1
  for (int t = 0; t + 2 < NKT; t += 2) {
    int ka = (t + 1) * 64;
    int kb = (t + 2) * 64;
    TILE(0, STG_B01(1, ka), STG_B23(1, ka), STG_A02(1, ka), STG_A13(1, ka), VM4, VM2);
    TILE(1, STG_B01(0, kb), STG_B23(0, kb), STG_A02(0, kb), STG_A13(0, kb), VM4, VM2);
  }
  {
    int ka = (NKT - 1) * 64;
    TILE(0, STG_B01(1, ka), STG_B23(1, ka), STG_A02(1, ka), STG_A13(1, ka), VM4, VM2);
    TILE(1, NOPW, NOPW, NOPW, NOPW, VM0, NOPW);  // last tile: drain before p2
  }

#undef STG_B01
#undef STG_B23
#undef STG_A02
#undef STG_A13
#undef PH
#undef TILE

  // epilogue: C/D map col=lane&15, row=(lane>>4)*4+r
#pragma unroll
  for (int m = 0; m < 8; m++) {
    int lrowb = wm * 128 + m * 16 + (lane >> 4) * 4;
#pragma unroll
    for (int r = 0; r < 4; r++) {
      int arow = m0 + lrowb + r;
      if (arow < cnt) {
        if constexpr (MODE == 1) {
          size_t rowbase = (size_t)(off + arow) * NDIM;
#pragma unroll
          for (int n = 0; n < 4; n++) {
            int col = nt * 256 + wn * 64 + n * 16 + (lane & 15);
            float v = acc[m][n][r] + bias[e * NDIM + col];
            v = v > 0.f ? v : 0.f;
            Hout[rowbase + col] = f2bf(v);
          }
        } else {
          int tok = ptok[off + arow];
          float g = pgate[off + arow];
#pragma unroll
          for (int n = 0; n < 4; n++) {
            int col = nt * 256 + wn * 64 + n * 16 + (lane & 15);
            float v = (acc[m][n][r] + bias[e * NDIM + col]) * g;
            atomicAdd(Out + (size_t)tok * D_DIM + col, v);
          }
        }
      }
    }
  }
}

extern "C" void kernel_launch(void* const* d_in, const int* in_sizes, int n_in,
                              void* d_out, int out_size, void* d_ws, size_t ws_size,
                              hipStream_t stream) {
  const float* x  = (const float*)d_in[0];
  const float* wg = (const float*)d_in[1];
  const float* bg = (const float*)d_in[2];
  const float* w1 = (const float*)d_in[3];
  const float* b1 = (const float*)d_in[4];
  const float* w2 = (const float*)d_in[5];
  const float* b2 = (const float*)d_in[6];
  float* out = (float*)d_out;

  char* ws = (char*)d_ws;
  unsigned short* xb = (unsigned short*)ws;   ws += (size_t)B_TOK * D_DIM * 2;
  unsigned short* w1t = (unsigned short*)ws;  ws += (size_t)E_NUM * D_DIM * H_DIM * 2;
  unsigned short* w2t = (unsigned short*)ws;  ws += (size_t)E_NUM * D_DIM * H_DIM * 2;
  unsigned short* Hbuf = (unsigned short*)ws; ws += (size_t)NPAIR * H_DIM * 2;
  int* tidx = (int*)ws;    ws += (size_t)NPAIR * 4;
  float* tgate = (float*)ws; ws += (size_t)NPAIR * 4;
  int* ptok = (int*)ws;    ws += (size_t)NPAIR * 4;
  float* pgate = (float*)ws; ws += (size_t)NPAIR * 4;
  int* meta = (int*)ws;  // cnt[8] | eoff[9] | cursor[8]
  int* cnt = meta;
  int* eoff = meta + 8;
  int* cursor = meta + 17;

  hipMemsetAsync(meta, 0, 32 * sizeof(int), stream);
  hipMemsetAsync(out, 0, (size_t)out_size * sizeof(float), stream);

  k_convert_x<<<(B_TOK * D_DIM) / 1024, 256, 0, stream>>>(x, xb);
  dim3 tb(32, 8);
  k_transpose_bf16<<<dim3(H_DIM / 32, D_DIM / 32, E_NUM), tb, 0, stream>>>(w1, w1t, D_DIM, H_DIM);
  k_transpose_bf16<<<dim3(D_DIM / 32, H_DIM / 32, E_NUM), tb, 0, stream>>>(w2, w2t, H_DIM, D_DIM);
  k_router<<<B_TOK / 4, 256, 0, stream>>>(x, wg, bg, tidx, tgate, cnt);
  k_prefix<<<1, 64, 0, stream>>>(cnt, eoff, cursor);
  k_scatter<<<B_TOK / 256, 256, 0, stream>>>(tidx, tgate, cursor, ptok, pgate);
  k_gemm<D_DIM, H_DIM, 1><<<E_NUM * (NPAIR / 256) * (H_DIM / 256), 512, 0, stream>>>(
      xb, w1t, b1, eoff, ptok, pgate, Hbuf, nullptr);
  k_gemm<H_DIM, D_DIM, 2><<<E_NUM * (NPAIR / 256) * (D_DIM / 256), 512, 0, stream>>>(
      Hbuf, w2t, b2, eoff, ptok, pgate, nullptr, out);
}